// Round 2
// baseline (988.135 us; speedup 1.0000x reference)
//
#include <hip/hip_runtime.h>

// SwinV2 window attention — fully fused: per-window qkv GEMM + attention + proj
// in ONE kernel. qkv never materialized to HBM.
// ws layout (bytes): [0,128K) biasfrag f32 | [128K,512K) w_t fp16[768][256]
//   | [512K,640K) p_t fp16[256][256]

typedef _Float16 f16;
typedef _Float16 f16x4 __attribute__((ext_vector_type(4)));
typedef _Float16 f16x8 __attribute__((ext_vector_type(8)));
typedef float f32x4 __attribute__((ext_vector_type(4)));

#define LOG100 4.6051701859880914f
#define EPS_L2 1.55e-5f

__device__ __forceinline__ int seg2(int p) { return (p >= 248) + (p >= 252); }

// ---------------- prep: CPB bias (in MFMA C-fragment order) + weight transpose/convert
__global__ __launch_bounds__(512) void k_prep(
    const float* __restrict__ cpb_w1, const float* __restrict__ cpb_b1,
    const float* __restrict__ cpb_w2, const float* __restrict__ qkv_w,
    const float* __restrict__ proj_w,
    float* __restrict__ biasfrag, f16* __restrict__ w_t, f16* __restrict__ p_t)
{
    __shared__ float cpb[225 * 8];
    int tid = threadIdx.x;
    if (blockIdx.x == 0) {
        if (tid < 225) {
            int a = tid / 15, b2 = tid % 15;
            float xa = (float)(a - 7) * (8.0f / 7.0f);
            float xb = (float)(b2 - 7) * (8.0f / 7.0f);
            float t0 = (xa < 0.f ? -1.f : 1.f) * log2f(1.0f + fabsf(xa)) * (1.0f / 3.0f);
            float t1 = (xb < 0.f ? -1.f : 1.f) * log2f(1.0f + fabsf(xb)) * (1.0f / 3.0f);
            float acc[8] = {0.f, 0.f, 0.f, 0.f, 0.f, 0.f, 0.f, 0.f};
            for (int j = 0; j < 512; ++j) {
                float hh = t0 * cpb_w1[j] + t1 * cpb_w1[512 + j] + cpb_b1[j];
                hh = fmaxf(hh, 0.0f);
                #pragma unroll
                for (int h = 0; h < 8; ++h) acc[h] += hh * cpb_w2[j * 8 + h];
            }
            #pragma unroll
            for (int h = 0; h < 8; ++h) cpb[tid * 8 + h] = acc[h];
        }
        __syncthreads();
        // biasfrag flat index f = (((h*4+mt)*4+nt)*64+lane)*4 + r
        for (int f = tid; f < 32768; f += 512) {
            int r = f & 3, lane = (f >> 2) & 63, nt = (f >> 8) & 3, mt = (f >> 10) & 3, h = (f >> 12) & 7;
            int q = mt * 16 + ((lane >> 4) << 2) + r;
            int k = nt * 16 + (lane & 15);
            int idx = ((q >> 3) - (k >> 3) + 7) * 15 + ((q & 7) - (k & 7) + 7);
            float c = cpb[idx * 8 + h];
            biasfrag[f] = 16.0f / (1.0f + expf(-c));
        }
    } else {
        int base = (blockIdx.x - 1) * 512 + tid;
        const int stride = 128 * 512;
        for (int i = base; i < 768 * 256; i += stride) {
            int n = i >> 8, k = i & 255;
            w_t[i] = (f16)qkv_w[k * 768 + n];     // w_t[n][k] = W[k][n]
        }
        for (int i = base; i < 256 * 256; i += stride) {
            int n = i >> 8, k = i & 255;
            p_t[i] = (f16)proj_w[k * 256 + n];
        }
    }
}

// ---------------- fused main: block = one window, wave = one head
// LDS: [0,32K) xt[64][256] f16 swizzled (later reused as ot[64][256])
//      [32K,64K) 8 x 4KB wave-private bounce buffers
__global__ __launch_bounds__(512, 4) void k_main(
    const float* __restrict__ x, const f16* __restrict__ w_t,
    const float* __restrict__ q_bias, const float* __restrict__ v_bias,
    const float* __restrict__ scale, const float* __restrict__ biasfrag,
    const f16* __restrict__ p_t, const float* __restrict__ proj_b,
    float* __restrict__ out)
{
    __shared__ char L[65536];
    const int tid = threadIdx.x;
    const int lane = tid & 63;
    const int h = tid >> 6;
    const int l15 = lane & 15;
    const int g = lane >> 4;
    const int bw = blockIdx.x;
    const int win = bw & 1023, b = bw >> 10;
    const int wh = win >> 5, ww = win & 31;
    char* wb = L + 32768 + (h << 12);
    const f32x4 fz = {0.f, 0.f, 0.f, 0.f};

    // ---- phase 0: stage rolled x window-tile -> xt (f16, swizzled)
    {
        int pos = tid >> 3, tc = tid & 7;
        int i2 = ((wh << 3) + (pos >> 3) + 4) & 255;
        int j2 = ((ww << 3) + (pos & 7) + 4) & 255;
        const float* xr = x + ((((long)b << 8) + i2) * 256 + j2) * 256;
        #pragma unroll
        for (int rep = 0; rep < 8; ++rep) {
            int ch = rep * 32 + tc * 4;
            float4 v = *reinterpret_cast<const float4*>(xr + ch);
            f16x4 hv = { (f16)v.x, (f16)v.y, (f16)v.z, (f16)v.w };
            *reinterpret_cast<f16x4*>(L + ((pos * 512 + ch * 2) ^ ((pos & 7) << 4))) = hv;
        }
    }
    __syncthreads();

    f16x8 qa[4], kb[4], vf[2][2];

    // ---- phase 1: qkv GEMM, wave h owns head-h columns of q,k,v (64x32 each, K=256)
    #pragma unroll 1
    for (int p = 0; p < 3; ++p) {
        f32x4 acc[4][2];
        #pragma unroll
        for (int mt = 0; mt < 4; ++mt) { acc[mt][0] = fz; acc[mt][1] = fz; }

        #pragma unroll
        for (int ks = 0; ks < 8; ++ks) {
            f16x8 a[4], bfr[2];
            #pragma unroll
            for (int mt = 0; mt < 4; ++mt) {
                int row = mt * 16 + l15;
                a[mt] = *reinterpret_cast<const f16x8*>(
                    L + ((row * 512 + ks * 64 + g * 16) ^ ((l15 & 7) << 4)));
            }
            #pragma unroll
            for (int nt = 0; nt < 2; ++nt)
                bfr[nt] = *reinterpret_cast<const f16x8*>(
                    w_t + ((p << 8) + (h << 5) + nt * 16 + l15) * 256 + ks * 32 + g * 8);
            #pragma unroll
            for (int mt = 0; mt < 4; ++mt)
                #pragma unroll
                for (int nt = 0; nt < 2; ++nt)
                    acc[mt][nt] = __builtin_amdgcn_mfma_f32_16x16x32_f16(a[mt], bfr[nt], acc[mt][nt], 0, 0, 0);
        }

        if (p == 0) {            // q: +bias, l2norm, *logit_scale -> bounce -> A-frags
            float ls = __expf(fminf(scale[h], LOG100));
            float b0 = q_bias[(h << 5) + l15], b1 = q_bias[(h << 5) + 16 + l15];
            #pragma unroll
            for (int mt = 0; mt < 4; ++mt)
                #pragma unroll
                for (int r = 0; r < 4; ++r) {
                    float a0 = acc[mt][0][r] + b0, a1 = acc[mt][1][r] + b1;
                    float s2 = a0 * a0 + a1 * a1;
                    s2 += __shfl_xor(s2, 1); s2 += __shfl_xor(s2, 2);
                    s2 += __shfl_xor(s2, 4); s2 += __shfl_xor(s2, 8);
                    float iv = ls / sqrtf(fmaxf(s2, EPS_L2));
                    int pos = mt * 16 + (g << 2) + r;
                    int sw = (pos & 7) << 4;
                    *reinterpret_cast<f16*>(wb + ((pos * 64 + l15 * 2) ^ sw)) = (f16)(a0 * iv);
                    *reinterpret_cast<f16*>(wb + ((pos * 64 + 32 + l15 * 2) ^ sw)) = (f16)(a1 * iv);
                }
            #pragma unroll
            for (int mt = 0; mt < 4; ++mt)
                qa[mt] = *reinterpret_cast<const f16x8*>(
                    wb + (((mt * 16 + l15) * 64 + g * 16) ^ ((l15 & 7) << 4)));
        } else if (p == 1) {     // k: l2norm -> bounce -> B-frags
            #pragma unroll
            for (int mt = 0; mt < 4; ++mt)
                #pragma unroll
                for (int r = 0; r < 4; ++r) {
                    float a0 = acc[mt][0][r], a1 = acc[mt][1][r];
                    float s2 = a0 * a0 + a1 * a1;
                    s2 += __shfl_xor(s2, 1); s2 += __shfl_xor(s2, 2);
                    s2 += __shfl_xor(s2, 4); s2 += __shfl_xor(s2, 8);
                    float iv = 1.0f / sqrtf(fmaxf(s2, EPS_L2));
                    int pos = mt * 16 + (g << 2) + r;
                    int sw = (pos & 7) << 4;
                    *reinterpret_cast<f16*>(wb + ((pos * 64 + l15 * 2) ^ sw)) = (f16)(a0 * iv);
                    *reinterpret_cast<f16*>(wb + ((pos * 64 + 32 + l15 * 2) ^ sw)) = (f16)(a1 * iv);
                }
            #pragma unroll
            for (int mt = 0; mt < 4; ++mt)
                kb[mt] = *reinterpret_cast<const f16x8*>(
                    wb + (((mt * 16 + l15) * 64 + g * 16) ^ ((l15 & 7) << 4)));
        } else {                 // v: +bias -> bounce as V^T[u][key] -> B-frags
            float b0 = v_bias[(h << 5) + l15], b1 = v_bias[(h << 5) + 16 + l15];
            #pragma unroll
            for (int mt = 0; mt < 4; ++mt)
                #pragma unroll
                for (int nt = 0; nt < 2; ++nt)
                    #pragma unroll
                    for (int r = 0; r < 4; ++r) {
                        float val = acc[mt][nt][r] + (nt ? b1 : b0);
                        int u = nt * 16 + l15;
                        int key = mt * 16 + (g << 2) + r;
                        *reinterpret_cast<f16*>(wb + ((u * 128 + key * 2) ^ ((u & 7) << 4))) = (f16)val;
                    }
            #pragma unroll
            for (int nt = 0; nt < 2; ++nt)
                #pragma unroll
                for (int ks = 0; ks < 2; ++ks)
                    vf[nt][ks] = *reinterpret_cast<const f16x8*>(
                        wb + (((nt * 16 + l15) * 128 + ks * 64 + g * 16) ^ ((l15 & 7) << 4)));
        }
    }

    // ---- phase 2: attention (wave-private). S, bias, mask, softmax; pack P to f16.
    const bool boundary = (wh == 31) || (ww == 31);
    f16x4 ph[4][4];
    float inv_[4][4];
    #pragma unroll
    for (int mt = 0; mt < 4; ++mt) {
        f32x4 sr[4];
        #pragma unroll
        for (int nt = 0; nt < 4; ++nt)
            sr[nt] = __builtin_amdgcn_mfma_f32_16x16x32_f16(qa[mt], kb[nt], fz, 0, 0, 0);
        #pragma unroll
        for (int nt = 0; nt < 4; ++nt)
            sr[nt] += *reinterpret_cast<const f32x4*>(
                biasfrag + ((((h * 4 + mt) * 4 + nt) * 64 + lane) << 2));
        if (boundary) {
            #pragma unroll
            for (int r = 0; r < 4; ++r) {
                int q = mt * 16 + (g << 2) + r;
                int lq = seg2((wh << 3) + (q >> 3)) * 3 + seg2((ww << 3) + (q & 7));
                #pragma unroll
                for (int nt = 0; nt < 4; ++nt) {
                    int k = nt * 16 + l15;
                    int lk = seg2((wh << 3) + (k >> 3)) * 3 + seg2((ww << 3) + (k & 7));
                    if (lq != lk) sr[nt][r] -= 100.0f;
                }
            }
        }
        #pragma unroll
        for (int r = 0; r < 4; ++r) {
            float mx = fmaxf(fmaxf(sr[0][r], sr[1][r]), fmaxf(sr[2][r], sr[3][r]));
            mx = fmaxf(mx, __shfl_xor(mx, 1));
            mx = fmaxf(mx, __shfl_xor(mx, 2));
            mx = fmaxf(mx, __shfl_xor(mx, 4));
            mx = fmaxf(mx, __shfl_xor(mx, 8));
            float sm = 0.f;
            #pragma unroll
            for (int nt = 0; nt < 4; ++nt) {
                float e = __expf(sr[nt][r] - mx);
                sr[nt][r] = e;
                sm += e;
            }
            sm += __shfl_xor(sm, 1); sm += __shfl_xor(sm, 2);
            sm += __shfl_xor(sm, 4); sm += __shfl_xor(sm, 8);
            inv_[mt][r] = 1.0f / sm;
        }
        #pragma unroll
        for (int nt = 0; nt < 4; ++nt)
            ph[mt][nt] = f16x4{ (f16)sr[nt][0], (f16)sr[nt][1], (f16)sr[nt][2], (f16)sr[nt][3] };
    }

    // ---- PV in two 32-key halves through the 4KB wave buffer
    f32x4 o[4][2];
    #pragma unroll
    for (int mt = 0; mt < 4; ++mt) { o[mt][0] = fz; o[mt][1] = fz; }
    #pragma unroll
    for (int half = 0; half < 2; ++half) {
        #pragma unroll
        for (int mt = 0; mt < 4; ++mt)
            #pragma unroll
            for (int nt2 = 0; nt2 < 2; ++nt2)
                #pragma unroll
                for (int r = 0; r < 4; ++r) {
                    int q = mt * 16 + (g << 2) + r;
                    int key = nt2 * 16 + l15;
                    *reinterpret_cast<f16*>(wb + ((q * 64 + key * 2) ^ ((q & 7) << 4))) =
                        ph[mt][half * 2 + nt2][r];
                }
        #pragma unroll
        for (int mt = 0; mt < 4; ++mt) {
            f16x8 pa = *reinterpret_cast<const f16x8*>(
                wb + (((mt * 16 + l15) * 64 + g * 16) ^ ((l15 & 7) << 4)));
            #pragma unroll
            for (int nt = 0; nt < 2; ++nt)
                o[mt][nt] = __builtin_amdgcn_mfma_f32_16x16x32_f16(pa, vf[nt][half], o[mt][nt], 0, 0, 0);
        }
    }

    // ---- phase 3: normalized O -> ot (reuse xt region), then fused proj
    __syncthreads();   // all waves done reading xt
    #pragma unroll
    for (int mt = 0; mt < 4; ++mt)
        #pragma unroll
        for (int r = 0; r < 4; ++r) {
            int q = mt * 16 + (g << 2) + r;
            float iv = inv_[mt][r];
            #pragma unroll
            for (int nt = 0; nt < 2; ++nt) {
                int ch = (h << 5) + nt * 16 + l15;
                *reinterpret_cast<f16*>(L + ((q * 512 + ch * 2) ^ ((q & 7) << 4))) =
                    (f16)(o[mt][nt][r] * iv);
            }
        }
    __syncthreads();

    f32x4 pc[4][2];
    #pragma unroll
    for (int mt = 0; mt < 4; ++mt) { pc[mt][0] = fz; pc[mt][1] = fz; }
    #pragma unroll
    for (int ks = 0; ks < 8; ++ks) {
        f16x8 a[4], bfr[2];
        #pragma unroll
        for (int mt = 0; mt < 4; ++mt) {
            int q = mt * 16 + l15;
            a[mt] = *reinterpret_cast<const f16x8*>(
                L + ((q * 512 + ks * 64 + g * 16) ^ ((l15 & 7) << 4)));
        }
        #pragma unroll
        for (int nt = 0; nt < 2; ++nt)
            bfr[nt] = *reinterpret_cast<const f16x8*>(
                p_t + ((h << 5) + nt * 16 + l15) * 256 + ks * 32 + g * 8);
        #pragma unroll
        for (int mt = 0; mt < 4; ++mt)
            #pragma unroll
            for (int nt = 0; nt < 2; ++nt)
                pc[mt][nt] = __builtin_amdgcn_mfma_f32_16x16x32_f16(a[mt], bfr[nt], pc[mt][nt], 0, 0, 0);
    }

    #pragma unroll
    for (int mt = 0; mt < 4; ++mt)
        #pragma unroll
        for (int r = 0; r < 4; ++r) {
            int q = mt * 16 + (g << 2) + r;
            int i = ((wh << 3) + (q >> 3) + 4) & 255;   // roll(+4) un-partition
            int j = ((ww << 3) + (q & 7) + 4) & 255;
            long addr = (((long)b * 256 + i) * 256 + j) * 256;
            #pragma unroll
            for (int nt = 0; nt < 2; ++nt) {
                int ch = (h << 5) + nt * 16 + l15;
                out[addr + ch] = pc[mt][nt][r] + proj_b[ch];
            }
        }
}

extern "C" void kernel_launch(void* const* d_in, const int* in_sizes, int n_in,
                              void* d_out, int out_size, void* d_ws, size_t ws_size,
                              hipStream_t stream) {
    const float* x      = (const float*)d_in[0];
    const float* qkv_w  = (const float*)d_in[1];
    const float* q_bias = (const float*)d_in[2];
    const float* v_bias = (const float*)d_in[3];
    const float* scale  = (const float*)d_in[4];
    const float* cpb_w1 = (const float*)d_in[5];
    const float* cpb_b1 = (const float*)d_in[6];
    const float* cpb_w2 = (const float*)d_in[7];
    const float* proj_w = (const float*)d_in[8];
    const float* proj_b = (const float*)d_in[9];
    float* out = (float*)d_out;

    char* ws = (char*)d_ws;
    float* biasfrag = (float*)(ws);                         // 128 KiB
    f16* w_t  = (f16*)(ws + 131072);                        // 384 KiB
    f16* p_t  = (f16*)(ws + 524288);                        // 128 KiB

    hipLaunchKernelGGL(k_prep, dim3(129), dim3(512), 0, stream,
                       cpb_w1, cpb_b1, cpb_w2, qkv_w, proj_w, biasfrag, w_t, p_t);
    hipLaunchKernelGGL(k_main, dim3(2048), dim3(512), 0, stream,
                       x, w_t, q_bias, v_bias, scale, biasfrag, p_t, proj_b, out);
}

// Round 3
// 464.679 us; speedup vs baseline: 2.1265x; 2.1265x over previous
//
#include <hip/hip_runtime.h>

// SwinV2 window attention — 3-kernel split with coalesced epilogues.
// ws layout (bytes): [0,128K) biasfrag f32 | [128K,512K) w_t fp16[768][256]
//   | [512K,640K) p_t fp16[256][256] | @1M qbuf 64M | kbuf 64M | vtbuf 64M

typedef _Float16 f16;
typedef _Float16 f16x4 __attribute__((ext_vector_type(4)));
typedef _Float16 f16x8 __attribute__((ext_vector_type(8)));
typedef float f32x4 __attribute__((ext_vector_type(4)));

#define LOG100 4.6051701859880914f
#define EPS_L2 1.55e-5f

__device__ __forceinline__ int seg2(int p) { return (p >= 248) + (p >= 252); }

// ---------------- prep: CPB bias (in MFMA C-fragment order) + weight transpose/convert
__global__ __launch_bounds__(512) void k_prep(
    const float* __restrict__ cpb_w1, const float* __restrict__ cpb_b1,
    const float* __restrict__ cpb_w2, const float* __restrict__ qkv_w,
    const float* __restrict__ proj_w,
    float* __restrict__ biasfrag, f16* __restrict__ w_t, f16* __restrict__ p_t)
{
    __shared__ float cpb[225 * 8];
    int tid = threadIdx.x;
    if (blockIdx.x == 0) {
        if (tid < 225) {
            int a = tid / 15, b2 = tid % 15;
            float xa = (float)(a - 7) * (8.0f / 7.0f);
            float xb = (float)(b2 - 7) * (8.0f / 7.0f);
            float t0 = (xa < 0.f ? -1.f : 1.f) * log2f(1.0f + fabsf(xa)) * (1.0f / 3.0f);
            float t1 = (xb < 0.f ? -1.f : 1.f) * log2f(1.0f + fabsf(xb)) * (1.0f / 3.0f);
            float acc[8] = {0.f, 0.f, 0.f, 0.f, 0.f, 0.f, 0.f, 0.f};
            for (int j = 0; j < 512; ++j) {
                float hh = t0 * cpb_w1[j] + t1 * cpb_w1[512 + j] + cpb_b1[j];
                hh = fmaxf(hh, 0.0f);
                #pragma unroll
                for (int h = 0; h < 8; ++h) acc[h] += hh * cpb_w2[j * 8 + h];
            }
            #pragma unroll
            for (int h = 0; h < 8; ++h) cpb[tid * 8 + h] = acc[h];
        }
        __syncthreads();
        // biasfrag flat index f = (((h*4+mt)*4+nt)*64+lane)*4 + r
        for (int f = tid; f < 32768; f += 512) {
            int r = f & 3, lane = (f >> 2) & 63, nt = (f >> 8) & 3, mt = (f >> 10) & 3, h = (f >> 12) & 7;
            int q = mt * 16 + ((lane >> 4) << 2) + r;
            int k = nt * 16 + (lane & 15);
            int idx = ((q >> 3) - (k >> 3) + 7) * 15 + ((q & 7) - (k & 7) + 7);
            float c = cpb[idx * 8 + h];
            biasfrag[f] = 16.0f / (1.0f + expf(-c));
        }
    } else {
        int base = (blockIdx.x - 1) * 512 + tid;
        const int stride = 128 * 512;
        for (int i = base; i < 768 * 256; i += stride) {
            int n = i >> 8, k = i & 255;
            w_t[i] = (f16)qkv_w[k * 768 + n];     // w_t[n][k] = W[k][n]
        }
        for (int i = base; i < 256 * 256; i += stride) {
            int n = i >> 8, k = i & 255;
            p_t[i] = (f16)proj_w[k * 256 + n];
        }
    }
}

// ---------------- K1: qkv GEMM + roll + partition + l2norm + coalesced layouts
// Block = 64 consecutive ROLLED pixels (roll absorbed into x read addresses).
// qbuf/kbuf: [b*1024+win][qq 64][ch 256] f16
// vtbuf:     [(b*1024+win)*8+h][kb 8][u 32][kk 8] f16
__global__ __launch_bounds__(512, 4) void k_qkv(
    const float* __restrict__ x, const f16* __restrict__ w_t,
    const float* __restrict__ q_bias, const float* __restrict__ v_bias,
    const float* __restrict__ scale,
    f16* __restrict__ qbuf, f16* __restrict__ kbuf, f16* __restrict__ vtbuf)
{
    __shared__ char L[65536];                 // [0,32K) x-tile f16; [32K,64K) bounce
    char* B1 = L + 32768;
    const int tid = threadIdx.x;
    const int lane = tid & 63;
    const int h = tid >> 6;                   // wave = 32-ch slice (= head within each matrix)
    const int l15 = lane & 15, g = lane >> 4;
    const int bid = blockIdx.x;
    const int b = bid >> 10, bid2 = bid & 1023;
    const int ip = bid2 >> 2;                 // rolled image row
    const int jp0 = (bid2 & 3) << 6;          // rolled col base (64-aligned)
    const int kb = ip & 7;                    // in-window row (same for whole block)
    const int iwin = ip >> 3;
    const f32x4 fz = {0.f, 0.f, 0.f, 0.f};

    // ---- stage x (rolled coords): 64 rows x 256 ch, f32 -> f16, swizzled
    {
        int row = tid >> 3, tc = tid & 7;
        int ix = (ip + 4) & 255;
        int jx = (jp0 + row + 4) & 255;
        const float* xr = x + ((((long)b << 8) + ix) * 256 + jx) * 256;
        int swz = (row & 7) << 4;
        #pragma unroll
        for (int rep = 0; rep < 4; ++rep) {
            int ch = rep * 64 + tc * 8;
            float4 v0 = *reinterpret_cast<const float4*>(xr + ch);
            float4 v1 = *reinterpret_cast<const float4*>(xr + ch + 4);
            f16x8 hv = { (f16)v0.x, (f16)v0.y, (f16)v0.z, (f16)v0.w,
                         (f16)v1.x, (f16)v1.y, (f16)v1.z, (f16)v1.w };
            *reinterpret_cast<f16x8*>(L + ((row * 512 + ch * 2) ^ swz)) = hv;
        }
    }
    __syncthreads();

    #pragma unroll 1
    for (int p = 0; p < 3; ++p) {             // q, k, v
        f32x4 acc[4][2];
        #pragma unroll
        for (int mt = 0; mt < 4; ++mt) { acc[mt][0] = fz; acc[mt][1] = fz; }

        #pragma unroll
        for (int ks = 0; ks < 8; ++ks) {
            f16x8 a[4], bf2[2];
            #pragma unroll
            for (int mt = 0; mt < 4; ++mt) {
                int row = mt * 16 + l15;
                a[mt] = *reinterpret_cast<const f16x8*>(
                    L + ((row * 512 + ks * 64 + g * 16) ^ ((row & 7) << 4)));
            }
            #pragma unroll
            for (int nt = 0; nt < 2; ++nt)
                bf2[nt] = *reinterpret_cast<const f16x8*>(
                    w_t + ((p << 8) + (h << 5) + nt * 16 + l15) * 256 + ks * 32 + g * 8);
            #pragma unroll
            for (int mt = 0; mt < 4; ++mt)
                #pragma unroll
                for (int nt = 0; nt < 2; ++nt)
                    acc[mt][nt] = __builtin_amdgcn_mfma_f32_16x16x32_f16(a[mt], bf2[nt], acc[mt][nt], 0, 0, 0);
        }

        __syncthreads();   // previous pass's bounce reads complete

        if (p < 2) {
            // q/k: (+bias), l2norm, (q: *logit_scale) -> bounce [row][256ch]
            float ls = 1.0f, b0 = 0.f, b1 = 0.f;
            if (p == 0) {
                ls = __expf(fminf(scale[h], LOG100));
                b0 = q_bias[(h << 5) + l15];
                b1 = q_bias[(h << 5) + 16 + l15];
            }
            #pragma unroll
            for (int mt = 0; mt < 4; ++mt)
                #pragma unroll
                for (int r = 0; r < 4; ++r) {
                    float a0 = acc[mt][0][r] + b0, a1 = acc[mt][1][r] + b1;
                    float s2 = a0 * a0 + a1 * a1;
                    s2 += __shfl_xor(s2, 1); s2 += __shfl_xor(s2, 2);
                    s2 += __shfl_xor(s2, 4); s2 += __shfl_xor(s2, 8);
                    float iv = ls / sqrtf(fmaxf(s2, EPS_L2));
                    int row = mt * 16 + (g << 2) + r;
                    int swz = (row & 7) << 4;
                    *reinterpret_cast<f16*>(B1 + ((row * 512 + ((h << 5) + l15) * 2) ^ swz)) = (f16)(a0 * iv);
                    *reinterpret_cast<f16*>(B1 + ((row * 512 + ((h << 5) + 16 + l15) * 2) ^ swz)) = (f16)(a1 * iv);
                }
            __syncthreads();
            // cooperative coalesced store: 512-B runs per row
            f16* dst = p ? kbuf : qbuf;
            int row = tid >> 3, tc = tid & 7;
            int win = (iwin << 5) | ((jp0 + row) >> 3);
            int qq = (kb << 3) | (row & 7);
            long base = (((long)((b << 10) | win)) * 64 + qq) * 256;
            int swz = (row & 7) << 4;
            #pragma unroll
            for (int i = 0; i < 4; ++i) {
                f16x8 vv = *reinterpret_cast<const f16x8*>(B1 + ((row * 512 + tc * 64 + i * 16) ^ swz));
                *reinterpret_cast<f16x8*>(dst + base + tc * 32 + i * 8) = vv;
            }
        } else {
            // v: +bias -> transposed bounce B2[ch 256][row 64]
            float b0 = v_bias[(h << 5) + l15], b1 = v_bias[(h << 5) + 16 + l15];
            #pragma unroll
            for (int mt = 0; mt < 4; ++mt)
                #pragma unroll
                for (int nt = 0; nt < 2; ++nt)
                    #pragma unroll
                    for (int r = 0; r < 4; ++r) {
                        float val = acc[mt][nt][r] + (nt ? b1 : b0);
                        int c = (h << 5) + nt * 16 + l15;
                        int row = mt * 16 + (g << 2) + r;
                        *reinterpret_cast<f16*>(B1 + ((c * 128 + row * 2) ^ ((c & 7) << 4))) = (f16)val;
                    }
            __syncthreads();
            // cooperative store: [win][h][kb][u][kk], 16-B chunks, u-coalesced
            int w = tid >> 6;                  // window (row oct)
            int hh = (tid & 63) >> 3;
            int uq = tid & 7;
            int win = (iwin << 5) | ((jp0 >> 3) + w);
            long vb = (((long)((b << 10) | win)) * 8 + hh) * 2048 + kb * 256;
            #pragma unroll
            for (int i = 0; i < 4; ++i) {
                int u = uq + i * 8;
                int c = (hh << 5) + u;
                f16x8 vv = *reinterpret_cast<const f16x8*>(B1 + ((c * 128 + w * 16) ^ ((c & 7) << 4)));
                *reinterpret_cast<f16x8*>(vtbuf + vb + u * 8) = vv;
            }
        }
    }
}

// ---------------- K2: per-window attention + fused proj, coalesced f32 output
__global__ __launch_bounds__(512, 4) void k_attn_proj(
    const f16* __restrict__ qbuf, const f16* __restrict__ kbuf,
    const f16* __restrict__ vtbuf, const float* __restrict__ biasfrag,
    const f16* __restrict__ p_t, const float* __restrict__ proj_b,
    float* __restrict__ out)
{
    __shared__ char L[65536];
    const int tid = threadIdx.x;
    const int lane = tid & 63;
    const int h = tid >> 6;
    const int l15 = lane & 15, g = lane >> 4;
    const int bw = blockIdx.x;
    const int win = bw & 1023, bb = bw >> 10;
    const int wh = win >> 5, ww = win & 31;
    const f32x4 fz = {0.f, 0.f, 0.f, 0.f};

    const f16* qp = qbuf + (long)bw * 16384 + h * 32;
    const f16* kp = kbuf + (long)bw * 16384 + h * 32;
    const f16* vp = vtbuf + ((long)bw * 8 + h) * 2048;

    f16x8 qa[4], kb[4], vf[2][2];
    #pragma unroll
    for (int t = 0; t < 4; ++t) {
        qa[t] = *reinterpret_cast<const f16x8*>(qp + (t * 16 + l15) * 256 + g * 8);
        kb[t] = *reinterpret_cast<const f16x8*>(kp + (t * 16 + l15) * 256 + g * 8);
    }
    #pragma unroll
    for (int nt = 0; nt < 2; ++nt)
        #pragma unroll
        for (int ks = 0; ks < 2; ++ks)
            vf[nt][ks] = *reinterpret_cast<const f16x8*>(
                vp + (ks * 4 + g) * 256 + (nt * 16 + l15) * 8);

    // ---- S = q.k^T + bias (+mask), softmax, pack P
    const bool boundary = (wh == 31) || (ww == 31);
    f16x4 ph[4][4];
    float inv_[4][4];
    #pragma unroll
    for (int mt = 0; mt < 4; ++mt) {
        f32x4 sr[4];
        #pragma unroll
        for (int nt = 0; nt < 4; ++nt)
            sr[nt] = __builtin_amdgcn_mfma_f32_16x16x32_f16(qa[mt], kb[nt], fz, 0, 0, 0);
        #pragma unroll
        for (int nt = 0; nt < 4; ++nt)
            sr[nt] += *reinterpret_cast<const f32x4*>(
                biasfrag + ((((h * 4 + mt) * 4 + nt) * 64 + lane) << 2));
        if (boundary) {
            #pragma unroll
            for (int r = 0; r < 4; ++r) {
                int q = mt * 16 + (g << 2) + r;
                int lq = seg2((wh << 3) + (q >> 3)) * 3 + seg2((ww << 3) + (q & 7));
                #pragma unroll
                for (int nt = 0; nt < 4; ++nt) {
                    int k = nt * 16 + l15;
                    int lk = seg2((wh << 3) + (k >> 3)) * 3 + seg2((ww << 3) + (k & 7));
                    if (lq != lk) sr[nt][r] -= 100.0f;
                }
            }
        }
        #pragma unroll
        for (int r = 0; r < 4; ++r) {
            float mx = fmaxf(fmaxf(sr[0][r], sr[1][r]), fmaxf(sr[2][r], sr[3][r]));
            mx = fmaxf(mx, __shfl_xor(mx, 1));
            mx = fmaxf(mx, __shfl_xor(mx, 2));
            mx = fmaxf(mx, __shfl_xor(mx, 4));
            mx = fmaxf(mx, __shfl_xor(mx, 8));
            float sm = 0.f;
            #pragma unroll
            for (int nt = 0; nt < 4; ++nt) {
                float e = __expf(sr[nt][r] - mx);
                sr[nt][r] = e;
                sm += e;
            }
            sm += __shfl_xor(sm, 1); sm += __shfl_xor(sm, 2);
            sm += __shfl_xor(sm, 4); sm += __shfl_xor(sm, 8);
            inv_[mt][r] = 1.0f / sm;
        }
        #pragma unroll
        for (int nt = 0; nt < 4; ++nt)
            ph[mt][nt] = f16x4{ (f16)sr[nt][0], (f16)sr[nt][1], (f16)sr[nt][2], (f16)sr[nt][3] };
    }

    // ---- P -> per-head 8KB LDS, PV (normalization deferred)
    char* Pb = L + (h << 13);
    #pragma unroll
    for (int mt = 0; mt < 4; ++mt)
        #pragma unroll
        for (int nt = 0; nt < 4; ++nt)
            #pragma unroll
            for (int r = 0; r < 4; ++r) {
                int q = mt * 16 + (g << 2) + r;
                int k = nt * 16 + l15;
                *reinterpret_cast<f16*>(Pb + ((q * 128 + k * 2) ^ ((q & 7) << 4))) = (f16)((float)ph[mt][nt][r]);
            }
    f32x4 o[4][2];
    #pragma unroll
    for (int mt = 0; mt < 4; ++mt) {
        int q = mt * 16 + l15;
        int swz = (q & 7) << 4;
        f16x8 pa0 = *reinterpret_cast<const f16x8*>(Pb + ((q * 128 + g * 16) ^ swz));
        f16x8 pa1 = *reinterpret_cast<const f16x8*>(Pb + ((q * 128 + 64 + g * 16) ^ swz));
        #pragma unroll
        for (int nt = 0; nt < 2; ++nt) {
            f32x4 t = __builtin_amdgcn_mfma_f32_16x16x32_f16(pa0, vf[nt][0], fz, 0, 0, 0);
            o[mt][nt] = __builtin_amdgcn_mfma_f32_16x16x32_f16(pa1, vf[nt][1], t, 0, 0, 0);
        }
    }
    __syncthreads();   // PV reads done before overwriting with ot

    // ---- normalized O -> ot[64][256] f16 (first 32K), fused proj
    #pragma unroll
    for (int mt = 0; mt < 4; ++mt)
        #pragma unroll
        for (int r = 0; r < 4; ++r) {
            int q = mt * 16 + (g << 2) + r;
            float iv = inv_[mt][r];
            #pragma unroll
            for (int nt = 0; nt < 2; ++nt) {
                int ch = (h << 5) + nt * 16 + l15;
                *reinterpret_cast<f16*>(L + ((q * 512 + ch * 2) ^ ((q & 7) << 4))) =
                    (f16)(o[mt][nt][r] * iv);
            }
        }
    __syncthreads();

    f32x4 pc[4][2];
    #pragma unroll
    for (int mt = 0; mt < 4; ++mt) { pc[mt][0] = fz; pc[mt][1] = fz; }
    #pragma unroll
    for (int ks = 0; ks < 8; ++ks) {
        f16x8 a[4], bfr[2];
        #pragma unroll
        for (int mt = 0; mt < 4; ++mt) {
            int q = mt * 16 + l15;
            a[mt] = *reinterpret_cast<const f16x8*>(
                L + ((q * 512 + ks * 64 + g * 16) ^ ((q & 7) << 4)));
        }
        #pragma unroll
        for (int nt = 0; nt < 2; ++nt)
            bfr[nt] = *reinterpret_cast<const f16x8*>(
                p_t + ((h << 5) + nt * 16 + l15) * 256 + ks * 32 + g * 8);
        #pragma unroll
        for (int mt = 0; mt < 4; ++mt)
            #pragma unroll
            for (int nt = 0; nt < 2; ++nt)
                pc[mt][nt] = __builtin_amdgcn_mfma_f32_16x16x32_f16(a[mt], bfr[nt], pc[mt][nt], 0, 0, 0);
    }
    __syncthreads();   // all proj A-frag reads done before f32 bounce overwrites L

    // ---- proj result -> f32 bounce [row][256ch] (full 64KB), coalesced store
    #pragma unroll
    for (int mt = 0; mt < 4; ++mt)
        #pragma unroll
        for (int r = 0; r < 4; ++r) {
            int row = mt * 16 + (g << 2) + r;
            int swz = (row & 7) << 4;
            #pragma unroll
            for (int nt = 0; nt < 2; ++nt) {
                int ch = (h << 5) + nt * 16 + l15;
                *reinterpret_cast<float*>(L + ((row * 1024 + ch * 4) ^ swz)) =
                    pc[mt][nt][r] + proj_b[ch];
            }
        }
    __syncthreads();
    {
        int row = tid >> 3, tc = tid & 7;
        int i = ((wh << 3) + (row >> 3) + 4) & 255;   // roll(+4) un-partition
        int j = ((ww << 3) + (row & 7) + 4) & 255;
        float* orow = out + (((long)bb * 256 + i) * 256 + j) * 256 + tc * 32;
        int swz = (row & 7) << 4;
        #pragma unroll
        for (int u = 0; u < 8; ++u) {
            f32x4 vv = *reinterpret_cast<const f32x4*>(L + ((row * 1024 + tc * 128 + u * 16) ^ swz));
            *reinterpret_cast<f32x4*>(orow + u * 4) = vv;
        }
    }
}

extern "C" void kernel_launch(void* const* d_in, const int* in_sizes, int n_in,
                              void* d_out, int out_size, void* d_ws, size_t ws_size,
                              hipStream_t stream) {
    const float* x      = (const float*)d_in[0];
    const float* qkv_w  = (const float*)d_in[1];
    const float* q_bias = (const float*)d_in[2];
    const float* v_bias = (const float*)d_in[3];
    const float* scale  = (const float*)d_in[4];
    const float* cpb_w1 = (const float*)d_in[5];
    const float* cpb_b1 = (const float*)d_in[6];
    const float* cpb_w2 = (const float*)d_in[7];
    const float* proj_w = (const float*)d_in[8];
    const float* proj_b = (const float*)d_in[9];
    float* out = (float*)d_out;

    char* ws = (char*)d_ws;
    float* biasfrag = (float*)(ws);                         // 128 KiB
    f16* w_t  = (f16*)(ws + 131072);                        // 384 KiB
    f16* p_t  = (f16*)(ws + 524288);                        // 128 KiB
    f16* qbuf = (f16*)(ws + (1u << 20));                    // 64 MiB
    f16* kbuf = (f16*)(ws + (1u << 20) + (1u << 26));       // 64 MiB
    f16* vtbuf = (f16*)(ws + (1u << 20) + 2u * (1u << 26)); // 64 MiB

    hipLaunchKernelGGL(k_prep, dim3(129), dim3(512), 0, stream,
                       cpb_w1, cpb_b1, cpb_w2, qkv_w, proj_w, biasfrag, w_t, p_t);
    hipLaunchKernelGGL(k_qkv, dim3(2048), dim3(512), 0, stream,
                       x, w_t, q_bias, v_bias, scale, qbuf, kbuf, vtbuf);
    hipLaunchKernelGGL(k_attn_proj, dim3(2048), dim3(512), 0, stream,
                       qbuf, kbuf, vtbuf, biasfrag, p_t, proj_b, out);
}

// Round 4
// 442.940 us; speedup vs baseline: 2.2309x; 1.0491x over previous
//
#include <hip/hip_runtime.h>

// SwinV2 window attention — 3-kernel split with coalesced epilogues.
// Round 4: launch_bounds (512,4) -> (512,2). VGPR 64 cap was forcing scratch
// spills (WRITE_SIZE 434MB vs 192 ideal); LDS already caps us at 2 blocks/CU,
// so 128 VGPR costs no occupancy.
// ws layout (bytes): [0,128K) biasfrag f32 | [128K,512K) w_t fp16[768][256]
//   | [512K,640K) p_t fp16[256][256] | @1M qbuf 64M | kbuf 64M | vtbuf 64M

typedef _Float16 f16;
typedef _Float16 f16x4 __attribute__((ext_vector_type(4)));
typedef _Float16 f16x8 __attribute__((ext_vector_type(8)));
typedef float f32x4 __attribute__((ext_vector_type(4)));

#define LOG100 4.6051701859880914f
#define EPS_L2 1.55e-5f

__device__ __forceinline__ int seg2(int p) { return (p >= 248) + (p >= 252); }

// ---------------- prep: CPB bias (in MFMA C-fragment order) + weight transpose/convert
__global__ __launch_bounds__(512) void k_prep(
    const float* __restrict__ cpb_w1, const float* __restrict__ cpb_b1,
    const float* __restrict__ cpb_w2, const float* __restrict__ qkv_w,
    const float* __restrict__ proj_w,
    float* __restrict__ biasfrag, f16* __restrict__ w_t, f16* __restrict__ p_t)
{
    __shared__ float cpb[225 * 8];
    int tid = threadIdx.x;
    if (blockIdx.x == 0) {
        if (tid < 225) {
            int a = tid / 15, b2 = tid % 15;
            float xa = (float)(a - 7) * (8.0f / 7.0f);
            float xb = (float)(b2 - 7) * (8.0f / 7.0f);
            float t0 = (xa < 0.f ? -1.f : 1.f) * log2f(1.0f + fabsf(xa)) * (1.0f / 3.0f);
            float t1 = (xb < 0.f ? -1.f : 1.f) * log2f(1.0f + fabsf(xb)) * (1.0f / 3.0f);
            float acc[8] = {0.f, 0.f, 0.f, 0.f, 0.f, 0.f, 0.f, 0.f};
            for (int j = 0; j < 512; ++j) {
                float hh = t0 * cpb_w1[j] + t1 * cpb_w1[512 + j] + cpb_b1[j];
                hh = fmaxf(hh, 0.0f);
                #pragma unroll
                for (int h = 0; h < 8; ++h) acc[h] += hh * cpb_w2[j * 8 + h];
            }
            #pragma unroll
            for (int h = 0; h < 8; ++h) cpb[tid * 8 + h] = acc[h];
        }
        __syncthreads();
        // biasfrag flat index f = (((h*4+mt)*4+nt)*64+lane)*4 + r
        for (int f = tid; f < 32768; f += 512) {
            int r = f & 3, lane = (f >> 2) & 63, nt = (f >> 8) & 3, mt = (f >> 10) & 3, h = (f >> 12) & 7;
            int q = mt * 16 + ((lane >> 4) << 2) + r;
            int k = nt * 16 + (lane & 15);
            int idx = ((q >> 3) - (k >> 3) + 7) * 15 + ((q & 7) - (k & 7) + 7);
            float c = cpb[idx * 8 + h];
            biasfrag[f] = 16.0f / (1.0f + expf(-c));
        }
    } else {
        int base = (blockIdx.x - 1) * 512 + tid;
        const int stride = 128 * 512;
        for (int i = base; i < 768 * 256; i += stride) {
            int n = i >> 8, k = i & 255;
            w_t[i] = (f16)qkv_w[k * 768 + n];     // w_t[n][k] = W[k][n]
        }
        for (int i = base; i < 256 * 256; i += stride) {
            int n = i >> 8, k = i & 255;
            p_t[i] = (f16)proj_w[k * 256 + n];
        }
    }
}

// ---------------- K1: qkv GEMM + roll + partition + l2norm + coalesced layouts
// Block = 64 consecutive ROLLED pixels (roll absorbed into x read addresses).
// qbuf/kbuf: [b*1024+win][qq 64][ch 256] f16
// vtbuf:     [(b*1024+win)*8+h][kb 8][u 32][kk 8] f16
__global__ __launch_bounds__(512, 2) void k_qkv(
    const float* __restrict__ x, const f16* __restrict__ w_t,
    const float* __restrict__ q_bias, const float* __restrict__ v_bias,
    const float* __restrict__ scale,
    f16* __restrict__ qbuf, f16* __restrict__ kbuf, f16* __restrict__ vtbuf)
{
    __shared__ char L[65536];                 // [0,32K) x-tile f16; [32K,64K) bounce
    char* B1 = L + 32768;
    const int tid = threadIdx.x;
    const int lane = tid & 63;
    const int h = tid >> 6;                   // wave = 32-ch slice (= head within each matrix)
    const int l15 = lane & 15, g = lane >> 4;
    const int bid = blockIdx.x;
    const int b = bid >> 10, bid2 = bid & 1023;
    const int ip = bid2 >> 2;                 // rolled image row
    const int jp0 = (bid2 & 3) << 6;          // rolled col base (64-aligned)
    const int kb = ip & 7;                    // in-window row (same for whole block)
    const int iwin = ip >> 3;
    const f32x4 fz = {0.f, 0.f, 0.f, 0.f};

    // ---- stage x (rolled coords): 64 rows x 256 ch, f32 -> f16, swizzled
    {
        int row = tid >> 3, tc = tid & 7;
        int ix = (ip + 4) & 255;
        int jx = (jp0 + row + 4) & 255;
        const float* xr = x + ((((long)b << 8) + ix) * 256 + jx) * 256;
        int swz = (row & 7) << 4;
        #pragma unroll
        for (int rep = 0; rep < 4; ++rep) {
            int ch = rep * 64 + tc * 8;
            float4 v0 = *reinterpret_cast<const float4*>(xr + ch);
            float4 v1 = *reinterpret_cast<const float4*>(xr + ch + 4);
            f16x8 hv = { (f16)v0.x, (f16)v0.y, (f16)v0.z, (f16)v0.w,
                         (f16)v1.x, (f16)v1.y, (f16)v1.z, (f16)v1.w };
            *reinterpret_cast<f16x8*>(L + ((row * 512 + ch * 2) ^ swz)) = hv;
        }
    }
    __syncthreads();

    #pragma unroll 1
    for (int p = 0; p < 3; ++p) {             // q, k, v
        f32x4 acc[4][2];
        #pragma unroll
        for (int mt = 0; mt < 4; ++mt) { acc[mt][0] = fz; acc[mt][1] = fz; }

        #pragma unroll
        for (int ks = 0; ks < 8; ++ks) {
            f16x8 a[4], bf2[2];
            #pragma unroll
            for (int mt = 0; mt < 4; ++mt) {
                int row = mt * 16 + l15;
                a[mt] = *reinterpret_cast<const f16x8*>(
                    L + ((row * 512 + ks * 64 + g * 16) ^ ((row & 7) << 4)));
            }
            #pragma unroll
            for (int nt = 0; nt < 2; ++nt)
                bf2[nt] = *reinterpret_cast<const f16x8*>(
                    w_t + ((p << 8) + (h << 5) + nt * 16 + l15) * 256 + ks * 32 + g * 8);
            #pragma unroll
            for (int mt = 0; mt < 4; ++mt)
                #pragma unroll
                for (int nt = 0; nt < 2; ++nt)
                    acc[mt][nt] = __builtin_amdgcn_mfma_f32_16x16x32_f16(a[mt], bf2[nt], acc[mt][nt], 0, 0, 0);
        }

        __syncthreads();   // previous pass's bounce reads complete

        if (p < 2) {
            // q/k: (+bias), l2norm, (q: *logit_scale) -> bounce [row][256ch]
            float ls = 1.0f, b0 = 0.f, b1 = 0.f;
            if (p == 0) {
                ls = __expf(fminf(scale[h], LOG100));
                b0 = q_bias[(h << 5) + l15];
                b1 = q_bias[(h << 5) + 16 + l15];
            }
            #pragma unroll
            for (int mt = 0; mt < 4; ++mt)
                #pragma unroll
                for (int r = 0; r < 4; ++r) {
                    float a0 = acc[mt][0][r] + b0, a1 = acc[mt][1][r] + b1;
                    float s2 = a0 * a0 + a1 * a1;
                    s2 += __shfl_xor(s2, 1); s2 += __shfl_xor(s2, 2);
                    s2 += __shfl_xor(s2, 4); s2 += __shfl_xor(s2, 8);
                    float iv = ls / sqrtf(fmaxf(s2, EPS_L2));
                    int row = mt * 16 + (g << 2) + r;
                    int swz = (row & 7) << 4;
                    *reinterpret_cast<f16*>(B1 + ((row * 512 + ((h << 5) + l15) * 2) ^ swz)) = (f16)(a0 * iv);
                    *reinterpret_cast<f16*>(B1 + ((row * 512 + ((h << 5) + 16 + l15) * 2) ^ swz)) = (f16)(a1 * iv);
                }
            __syncthreads();
            // cooperative coalesced store: 512-B runs per row
            f16* dst = p ? kbuf : qbuf;
            int row = tid >> 3, tc = tid & 7;
            int win = (iwin << 5) | ((jp0 + row) >> 3);
            int qq = (kb << 3) | (row & 7);
            long base = (((long)((b << 10) | win)) * 64 + qq) * 256;
            int swz = (row & 7) << 4;
            #pragma unroll
            for (int i = 0; i < 4; ++i) {
                f16x8 vv = *reinterpret_cast<const f16x8*>(B1 + ((row * 512 + tc * 64 + i * 16) ^ swz));
                *reinterpret_cast<f16x8*>(dst + base + tc * 32 + i * 8) = vv;
            }
        } else {
            // v: +bias -> transposed bounce B2[ch 256][row 64]
            float b0 = v_bias[(h << 5) + l15], b1 = v_bias[(h << 5) + 16 + l15];
            #pragma unroll
            for (int mt = 0; mt < 4; ++mt)
                #pragma unroll
                for (int nt = 0; nt < 2; ++nt)
                    #pragma unroll
                    for (int r = 0; r < 4; ++r) {
                        float val = acc[mt][nt][r] + (nt ? b1 : b0);
                        int c = (h << 5) + nt * 16 + l15;
                        int row = mt * 16 + (g << 2) + r;
                        *reinterpret_cast<f16*>(B1 + ((c * 128 + row * 2) ^ ((c & 7) << 4))) = (f16)val;
                    }
            __syncthreads();
            // cooperative store: [win][h][kb][u][kk], 16-B chunks, u-coalesced
            int w = tid >> 6;                  // window (row oct)
            int hh = (tid & 63) >> 3;
            int uq = tid & 7;
            int win = (iwin << 5) | ((jp0 >> 3) + w);
            long vb = (((long)((b << 10) | win)) * 8 + hh) * 2048 + kb * 256;
            #pragma unroll
            for (int i = 0; i < 4; ++i) {
                int u = uq + i * 8;
                int c = (hh << 5) + u;
                f16x8 vv = *reinterpret_cast<const f16x8*>(B1 + ((c * 128 + w * 16) ^ ((c & 7) << 4)));
                *reinterpret_cast<f16x8*>(vtbuf + vb + u * 8) = vv;
            }
        }
    }
}

// ---------------- K2: per-window attention + fused proj, coalesced f32 output
__global__ __launch_bounds__(512, 2) void k_attn_proj(
    const f16* __restrict__ qbuf, const f16* __restrict__ kbuf,
    const f16* __restrict__ vtbuf, const float* __restrict__ biasfrag,
    const f16* __restrict__ p_t, const float* __restrict__ proj_b,
    float* __restrict__ out)
{
    __shared__ char L[65536];
    const int tid = threadIdx.x;
    const int lane = tid & 63;
    const int h = tid >> 6;
    const int l15 = lane & 15, g = lane >> 4;
    const int bw = blockIdx.x;
    const int win = bw & 1023, bb = bw >> 10;
    const int wh = win >> 5, ww = win & 31;
    const f32x4 fz = {0.f, 0.f, 0.f, 0.f};

    const f16* qp = qbuf + (long)bw * 16384 + h * 32;
    const f16* kp = kbuf + (long)bw * 16384 + h * 32;
    const f16* vp = vtbuf + ((long)bw * 8 + h) * 2048;

    f16x8 qa[4], kb[4], vf[2][2];
    #pragma unroll
    for (int t = 0; t < 4; ++t) {
        qa[t] = *reinterpret_cast<const f16x8*>(qp + (t * 16 + l15) * 256 + g * 8);
        kb[t] = *reinterpret_cast<const f16x8*>(kp + (t * 16 + l15) * 256 + g * 8);
    }
    #pragma unroll
    for (int nt = 0; nt < 2; ++nt)
        #pragma unroll
        for (int ks = 0; ks < 2; ++ks)
            vf[nt][ks] = *reinterpret_cast<const f16x8*>(
                vp + (ks * 4 + g) * 256 + (nt * 16 + l15) * 8);

    // ---- S = q.k^T + bias (+mask), softmax, pack P
    const bool boundary = (wh == 31) || (ww == 31);
    f16x4 ph[4][4];
    float inv_[4][4];
    #pragma unroll
    for (int mt = 0; mt < 4; ++mt) {
        f32x4 sr[4];
        #pragma unroll
        for (int nt = 0; nt < 4; ++nt)
            sr[nt] = __builtin_amdgcn_mfma_f32_16x16x32_f16(qa[mt], kb[nt], fz, 0, 0, 0);
        #pragma unroll
        for (int nt = 0; nt < 4; ++nt)
            sr[nt] += *reinterpret_cast<const f32x4*>(
                biasfrag + ((((h * 4 + mt) * 4 + nt) * 64 + lane) << 2));
        if (boundary) {
            #pragma unroll
            for (int r = 0; r < 4; ++r) {
                int q = mt * 16 + (g << 2) + r;
                int lq = seg2((wh << 3) + (q >> 3)) * 3 + seg2((ww << 3) + (q & 7));
                #pragma unroll
                for (int nt = 0; nt < 4; ++nt) {
                    int k = nt * 16 + l15;
                    int lk = seg2((wh << 3) + (k >> 3)) * 3 + seg2((ww << 3) + (k & 7));
                    if (lq != lk) sr[nt][r] -= 100.0f;
                }
            }
        }
        #pragma unroll
        for (int r = 0; r < 4; ++r) {
            float mx = fmaxf(fmaxf(sr[0][r], sr[1][r]), fmaxf(sr[2][r], sr[3][r]));
            mx = fmaxf(mx, __shfl_xor(mx, 1));
            mx = fmaxf(mx, __shfl_xor(mx, 2));
            mx = fmaxf(mx, __shfl_xor(mx, 4));
            mx = fmaxf(mx, __shfl_xor(mx, 8));
            float sm = 0.f;
            #pragma unroll
            for (int nt = 0; nt < 4; ++nt) {
                float e = __expf(sr[nt][r] - mx);
                sr[nt][r] = e;
                sm += e;
            }
            sm += __shfl_xor(sm, 1); sm += __shfl_xor(sm, 2);
            sm += __shfl_xor(sm, 4); sm += __shfl_xor(sm, 8);
            inv_[mt][r] = 1.0f / sm;
        }
        #pragma unroll
        for (int nt = 0; nt < 4; ++nt)
            ph[mt][nt] = f16x4{ (f16)sr[nt][0], (f16)sr[nt][1], (f16)sr[nt][2], (f16)sr[nt][3] };
    }

    // ---- P -> per-head 8KB LDS, PV (normalization deferred)
    char* Pb = L + (h << 13);
    #pragma unroll
    for (int mt = 0; mt < 4; ++mt)
        #pragma unroll
        for (int nt = 0; nt < 4; ++nt)
            #pragma unroll
            for (int r = 0; r < 4; ++r) {
                int q = mt * 16 + (g << 2) + r;
                int k = nt * 16 + l15;
                *reinterpret_cast<f16*>(Pb + ((q * 128 + k * 2) ^ ((q & 7) << 4))) = (f16)((float)ph[mt][nt][r]);
            }
    f32x4 o[4][2];
    #pragma unroll
    for (int mt = 0; mt < 4; ++mt) {
        int q = mt * 16 + l15;
        int swz = (q & 7) << 4;
        f16x8 pa0 = *reinterpret_cast<const f16x8*>(Pb + ((q * 128 + g * 16) ^ swz));
        f16x8 pa1 = *reinterpret_cast<const f16x8*>(Pb + ((q * 128 + 64 + g * 16) ^ swz));
        #pragma unroll
        for (int nt = 0; nt < 2; ++nt) {
            f32x4 t = __builtin_amdgcn_mfma_f32_16x16x32_f16(pa0, vf[nt][0], fz, 0, 0, 0);
            o[mt][nt] = __builtin_amdgcn_mfma_f32_16x16x32_f16(pa1, vf[nt][1], t, 0, 0, 0);
        }
    }
    __syncthreads();   // PV reads done before overwriting with ot

    // ---- normalized O -> ot[64][256] f16 (first 32K), fused proj
    #pragma unroll
    for (int mt = 0; mt < 4; ++mt)
        #pragma unroll
        for (int r = 0; r < 4; ++r) {
            int q = mt * 16 + (g << 2) + r;
            float iv = inv_[mt][r];
            #pragma unroll
            for (int nt = 0; nt < 2; ++nt) {
                int ch = (h << 5) + nt * 16 + l15;
                *reinterpret_cast<f16*>(L + ((q * 512 + ch * 2) ^ ((q & 7) << 4))) =
                    (f16)(o[mt][nt][r] * iv);
            }
        }
    __syncthreads();

    f32x4 pc[4][2];
    #pragma unroll
    for (int mt = 0; mt < 4; ++mt) { pc[mt][0] = fz; pc[mt][1] = fz; }
    #pragma unroll
    for (int ks = 0; ks < 8; ++ks) {
        f16x8 a[4], bfr[2];
        #pragma unroll
        for (int mt = 0; mt < 4; ++mt) {
            int q = mt * 16 + l15;
            a[mt] = *reinterpret_cast<const f16x8*>(
                L + ((q * 512 + ks * 64 + g * 16) ^ ((q & 7) << 4)));
        }
        #pragma unroll
        for (int nt = 0; nt < 2; ++nt)
            bfr[nt] = *reinterpret_cast<const f16x8*>(
                p_t + ((h << 5) + nt * 16 + l15) * 256 + ks * 32 + g * 8);
        #pragma unroll
        for (int mt = 0; mt < 4; ++mt)
            #pragma unroll
            for (int nt = 0; nt < 2; ++nt)
                pc[mt][nt] = __builtin_amdgcn_mfma_f32_16x16x32_f16(a[mt], bfr[nt], pc[mt][nt], 0, 0, 0);
    }
    __syncthreads();   // all proj A-frag reads done before f32 bounce overwrites L

    // ---- proj result -> f32 bounce [row][256ch] (full 64KB), coalesced store
    #pragma unroll
    for (int mt = 0; mt < 4; ++mt)
        #pragma unroll
        for (int r = 0; r < 4; ++r) {
            int row = mt * 16 + (g << 2) + r;
            int swz = (row & 7) << 4;
            #pragma unroll
            for (int nt = 0; nt < 2; ++nt) {
                int ch = (h << 5) + nt * 16 + l15;
                *reinterpret_cast<float*>(L + ((row * 1024 + ch * 4) ^ swz)) =
                    pc[mt][nt][r] + proj_b[ch];
            }
        }
    __syncthreads();
    {
        int row = tid >> 3, tc = tid & 7;
        int i = ((wh << 3) + (row >> 3) + 4) & 255;   // roll(+4) un-partition
        int j = ((ww << 3) + (row & 7) + 4) & 255;
        float* orow = out + (((long)bb * 256 + i) * 256 + j) * 256 + tc * 32;
        int swz = (row & 7) << 4;
        #pragma unroll
        for (int u = 0; u < 8; ++u) {
            f32x4 vv = *reinterpret_cast<const f32x4*>(L + ((row * 1024 + tc * 128 + u * 16) ^ swz));
            *reinterpret_cast<f32x4*>(orow + u * 4) = vv;
        }
    }
}

extern "C" void kernel_launch(void* const* d_in, const int* in_sizes, int n_in,
                              void* d_out, int out_size, void* d_ws, size_t ws_size,
                              hipStream_t stream) {
    const float* x      = (const float*)d_in[0];
    const float* qkv_w  = (const float*)d_in[1];
    const float* q_bias = (const float*)d_in[2];
    const float* v_bias = (const float*)d_in[3];
    const float* scale  = (const float*)d_in[4];
    const float* cpb_w1 = (const float*)d_in[5];
    const float* cpb_b1 = (const float*)d_in[6];
    const float* cpb_w2 = (const float*)d_in[7];
    const float* proj_w = (const float*)d_in[8];
    const float* proj_b = (const float*)d_in[9];
    float* out = (float*)d_out;

    char* ws = (char*)d_ws;
    float* biasfrag = (float*)(ws);                         // 128 KiB
    f16* w_t  = (f16*)(ws + 131072);                        // 384 KiB
    f16* p_t  = (f16*)(ws + 524288);                        // 128 KiB
    f16* qbuf = (f16*)(ws + (1u << 20));                    // 64 MiB
    f16* kbuf = (f16*)(ws + (1u << 20) + (1u << 26));       // 64 MiB
    f16* vtbuf = (f16*)(ws + (1u << 20) + 2u * (1u << 26)); // 64 MiB

    hipLaunchKernelGGL(k_prep, dim3(129), dim3(512), 0, stream,
                       cpb_w1, cpb_b1, cpb_w2, qkv_w, proj_w, biasfrag, w_t, p_t);
    hipLaunchKernelGGL(k_qkv, dim3(2048), dim3(512), 0, stream,
                       x, w_t, q_bias, v_bias, scale, qbuf, kbuf, vtbuf);
    hipLaunchKernelGGL(k_attn_proj, dim3(2048), dim3(512), 0, stream,
                       qbuf, kbuf, vtbuf, biasfrag, p_t, proj_b, out);
}

// Round 5
// 352.333 us; speedup vs baseline: 2.8045x; 1.2572x over previous
//
#include <hip/hip_runtime.h>

// SwinV2 window attention — 3-kernel split, round 5: wave-independent epilogues.
// 256-thr blocks, 48 KiB LDS (32K shared stage + 4x4K wave-private bounce),
// ONE barrier per kernel. Waves own 32-ch output strips end-to-end.
// ws layout: [0,128K) biasfrag f32 | [128K,512K) w_t fp16[768][256]
//   | [512K,640K) p_t fp16[256][256] | @1M qbuf 64M | kbuf 64M | vtbuf 64M

typedef _Float16 f16;
typedef _Float16 f16x4 __attribute__((ext_vector_type(4)));
typedef _Float16 f16x8 __attribute__((ext_vector_type(8)));
typedef float f32x4 __attribute__((ext_vector_type(4)));

#define LOG100 4.6051701859880914f
#define EPS_L2 1.55e-5f

__device__ __forceinline__ int seg2(int p) { return (p >= 248) + (p >= 252); }

// ---------------- prep: CPB bias (in MFMA C-fragment order) + weight transpose/convert
__global__ __launch_bounds__(512) void k_prep(
    const float* __restrict__ cpb_w1, const float* __restrict__ cpb_b1,
    const float* __restrict__ cpb_w2, const float* __restrict__ qkv_w,
    const float* __restrict__ proj_w,
    float* __restrict__ biasfrag, f16* __restrict__ w_t, f16* __restrict__ p_t)
{
    __shared__ float cpb[225 * 8];
    int tid = threadIdx.x;
    if (blockIdx.x == 0) {
        if (tid < 225) {
            int a = tid / 15, b2 = tid % 15;
            float xa = (float)(a - 7) * (8.0f / 7.0f);
            float xb = (float)(b2 - 7) * (8.0f / 7.0f);
            float t0 = (xa < 0.f ? -1.f : 1.f) * log2f(1.0f + fabsf(xa)) * (1.0f / 3.0f);
            float t1 = (xb < 0.f ? -1.f : 1.f) * log2f(1.0f + fabsf(xb)) * (1.0f / 3.0f);
            float acc[8] = {0.f, 0.f, 0.f, 0.f, 0.f, 0.f, 0.f, 0.f};
            for (int j = 0; j < 512; ++j) {
                float hh = t0 * cpb_w1[j] + t1 * cpb_w1[512 + j] + cpb_b1[j];
                hh = fmaxf(hh, 0.0f);
                #pragma unroll
                for (int h = 0; h < 8; ++h) acc[h] += hh * cpb_w2[j * 8 + h];
            }
            #pragma unroll
            for (int h = 0; h < 8; ++h) cpb[tid * 8 + h] = acc[h];
        }
        __syncthreads();
        for (int f = tid; f < 32768; f += 512) {
            int r = f & 3, lane = (f >> 2) & 63, nt = (f >> 8) & 3, mt = (f >> 10) & 3, h = (f >> 12) & 7;
            int q = mt * 16 + ((lane >> 4) << 2) + r;
            int k = nt * 16 + (lane & 15);
            int idx = ((q >> 3) - (k >> 3) + 7) * 15 + ((q & 7) - (k & 7) + 7);
            float c = cpb[idx * 8 + h];
            biasfrag[f] = 16.0f / (1.0f + expf(-c));
        }
    } else {
        int base = (blockIdx.x - 1) * 512 + tid;
        const int stride = 128 * 512;
        for (int i = base; i < 768 * 256; i += stride) {
            int n = i >> 8, k = i & 255;
            w_t[i] = (f16)qkv_w[k * 768 + n];     // w_t[n][k] = W[k][n]
        }
        for (int i = base; i < 256 * 256; i += stride) {
            int n = i >> 8, k = i & 255;
            p_t[i] = (f16)proj_w[k * 256 + n];
        }
    }
}

// ---------------- K1: qkv GEMM. Block = 64 rolled pixels (one image row segment).
// 4 waves; wave does 6 of the 24 32-ch strips (q0..7,k0..7,v0..7), private epilogue.
// qbuf/kbuf: [b*1024+win][qq 64][ch 256] f16
// vtbuf:     [(b*1024+win)*8+h][kb 8][u 32][kk 8] f16
__global__ __launch_bounds__(256, 2) void k_qkv(
    const float* __restrict__ x, const f16* __restrict__ w_t,
    const float* __restrict__ q_bias, const float* __restrict__ v_bias,
    const float* __restrict__ scale,
    f16* __restrict__ qbuf, f16* __restrict__ kbuf, f16* __restrict__ vtbuf)
{
    __shared__ char L[49152];                 // [0,32K) x-tile; [32K,48K) 4x4K wave bounce
    const int tid = threadIdx.x;
    const int lane = tid & 63;
    const int wv = tid >> 6;
    const int l15 = lane & 15, g = lane >> 4;
    const int bid = blockIdx.x;
    const int b = bid >> 10, bid2 = bid & 1023;
    const int ip = bid2 >> 2;                 // rolled image row
    const int jp0 = (bid2 & 3) << 6;          // rolled col base
    const int kb = ip & 7;                    // in-window i
    const int iwin = ip >> 3;
    char* wb = L + 32768 + (wv << 12);
    const f32x4 fz = {0.f, 0.f, 0.f, 0.f};

    // ---- stage x (rolled coords): 64 pixels x 256 ch, f32 -> f16, swizzled
    {
        int row = tid >> 2, tc = tid & 3;
        int ix = (ip + 4) & 255;
        int jx = (jp0 + row + 4) & 255;
        const float* xr = x + ((((long)b << 8) + ix) * 256 + jx) * 256;
        int swz = (row & 7) << 4;
        #pragma unroll
        for (int rep = 0; rep < 8; ++rep) {
            int ch = rep * 32 + tc * 8;
            float4 v0 = *reinterpret_cast<const float4*>(xr + ch);
            float4 v1 = *reinterpret_cast<const float4*>(xr + ch + 4);
            f16x8 hv = { (f16)v0.x, (f16)v0.y, (f16)v0.z, (f16)v0.w,
                         (f16)v1.x, (f16)v1.y, (f16)v1.z, (f16)v1.w };
            *reinterpret_cast<f16x8*>(L + ((row * 512 + ch * 2) ^ swz)) = hv;
        }
    }
    __syncthreads();   // the ONLY block barrier

    #pragma unroll 1
    for (int sp = 0; sp < 6; ++sp) {
        const int s = sp * 4 + wv;            // strip 0..23
        const int p = s >> 3, h = s & 7;      // matrix, head
        f32x4 acc[4][2];
        #pragma unroll
        for (int mt = 0; mt < 4; ++mt) { acc[mt][0] = fz; acc[mt][1] = fz; }

        #pragma unroll
        for (int ks = 0; ks < 8; ++ks) {
            f16x8 a[4], bf2[2];
            #pragma unroll
            for (int mt = 0; mt < 4; ++mt) {
                int row = mt * 16 + l15;
                a[mt] = *reinterpret_cast<const f16x8*>(
                    L + ((row * 512 + ks * 64 + g * 16) ^ ((row & 7) << 4)));
            }
            #pragma unroll
            for (int nt = 0; nt < 2; ++nt)
                bf2[nt] = *reinterpret_cast<const f16x8*>(
                    w_t + (s * 32 + nt * 16 + l15) * 256 + ks * 32 + g * 8);
            #pragma unroll
            for (int mt = 0; mt < 4; ++mt)
                #pragma unroll
                for (int nt = 0; nt < 2; ++nt)
                    acc[mt][nt] = __builtin_amdgcn_mfma_f32_16x16x32_f16(a[mt], bf2[nt], acc[mt][nt], 0, 0, 0);
        }

        if (p < 2) {
            // q/k: (+bias), l2norm, (q: *logit_scale) -> wave bounce [pix 64][ch 32]
            float ls = 1.0f, b0 = 0.f, b1 = 0.f;
            if (p == 0) {
                ls = __expf(fminf(scale[h], LOG100));
                b0 = q_bias[(h << 5) + l15];
                b1 = q_bias[(h << 5) + 16 + l15];
            }
            #pragma unroll
            for (int mt = 0; mt < 4; ++mt)
                #pragma unroll
                for (int r = 0; r < 4; ++r) {
                    float a0 = acc[mt][0][r] + b0, a1 = acc[mt][1][r] + b1;
                    float s2 = a0 * a0 + a1 * a1;
                    s2 += __shfl_xor(s2, 1); s2 += __shfl_xor(s2, 2);
                    s2 += __shfl_xor(s2, 4); s2 += __shfl_xor(s2, 8);
                    float iv = ls / sqrtf(fmaxf(s2, EPS_L2));
                    int row = mt * 16 + (g << 2) + r;
                    int swz = (row & 3) << 4;
                    *reinterpret_cast<f16*>(wb + ((row * 64 + l15 * 2) ^ swz)) = (f16)(a0 * iv);
                    *reinterpret_cast<f16*>(wb + ((row * 64 + 32 + l15 * 2) ^ swz)) = (f16)(a1 * iv);
                }
            // wave-coalesced store: 8 x 64-B segments per instr
            f16* dst = p ? kbuf : qbuf;
            #pragma unroll
            for (int i = 0; i < 8; ++i) {
                int row = i * 8 + (lane >> 3);
                int c4 = (lane & 7) * 4;
                f16x4 vv = *reinterpret_cast<const f16x4*>(
                    wb + ((row * 64 + c4 * 2) ^ ((row & 3) << 4)));
                int win = (iwin << 5) | ((jp0 + row) >> 3);
                long base = (((long)((b << 10) | win)) * 64 + (kb << 3) + (row & 7)) * 256;
                *reinterpret_cast<f16x4*>(dst + base + (h << 5) + c4) = vv;
            }
        } else {
            // v: +bias -> wave bounce transposed [u 32][pix 64]
            float b0 = v_bias[(h << 5) + l15], b1 = v_bias[(h << 5) + 16 + l15];
            #pragma unroll
            for (int mt = 0; mt < 4; ++mt)
                #pragma unroll
                for (int nt = 0; nt < 2; ++nt)
                    #pragma unroll
                    for (int r = 0; r < 4; ++r) {
                        float val = acc[mt][nt][r] + (nt ? b1 : b0);
                        int u = nt * 16 + l15;
                        int pix = mt * 16 + (g << 2) + r;
                        *reinterpret_cast<f16*>(wb + ((u * 128 + pix * 2) ^ ((u & 7) << 4))) = (f16)val;
                    }
            // store: per window contiguous 512 B ([u 32][kk 8])
            #pragma unroll
            for (int w2 = 0; w2 < 8; ++w2) {
                int u = lane >> 1, kk = (lane & 1) * 4;
                f16x4 vv = *reinterpret_cast<const f16x4*>(
                    wb + ((u * 128 + (w2 * 8 + kk) * 2) ^ ((u & 7) << 4)));
                int win = (iwin << 5) | ((jp0 >> 3) + w2);
                *reinterpret_cast<f16x4*>(
                    vtbuf + (((long)((b << 10) | win)) * 8 + h) * 2048 + kb * 256 + u * 8 + kk) = vv;
            }
        }
    }
}

// ---------------- K2: per-window attention + fused proj. 4 waves; wave = 2 heads.
__global__ __launch_bounds__(256, 2) void k_attn_proj(
    const f16* __restrict__ qbuf, const f16* __restrict__ kbuf,
    const f16* __restrict__ vtbuf, const float* __restrict__ biasfrag,
    const f16* __restrict__ p_t, const float* __restrict__ proj_b,
    float* __restrict__ out)
{
    __shared__ char L[49152];                 // [0,32K) ot[64][256] f16; [32K,48K) bounce
    const int tid = threadIdx.x;
    const int lane = tid & 63;
    const int wv = tid >> 6;
    const int l15 = lane & 15, g = lane >> 4;
    const int bw = blockIdx.x;
    const int win = bw & 1023, bb = bw >> 10;
    const int wh = win >> 5, ww = win & 31;
    char* wb = L + 32768 + (wv << 12);
    const f32x4 fz = {0.f, 0.f, 0.f, 0.f};
    const bool boundary = (wh == 31) || (ww == 31);

    #pragma unroll 1
    for (int hh = 0; hh < 2; ++hh) {
        const int h = wv + hh * 4;
        const f16* qp = qbuf + (long)bw * 16384 + h * 32;
        const f16* kp = kbuf + (long)bw * 16384 + h * 32;
        const f16* vp = vtbuf + ((long)bw * 8 + h) * 2048;

        f16x8 qa[4], kb[4];
        #pragma unroll
        for (int t = 0; t < 4; ++t) {
            qa[t] = *reinterpret_cast<const f16x8*>(qp + (t * 16 + l15) * 256 + g * 8);
            kb[t] = *reinterpret_cast<const f16x8*>(kp + (t * 16 + l15) * 256 + g * 8);
        }

        f16x4 ph[4][4];
        float inv_[4][4];
        #pragma unroll
        for (int mt = 0; mt < 4; ++mt) {
            f32x4 sr[4];
            #pragma unroll
            for (int nt = 0; nt < 4; ++nt)
                sr[nt] = __builtin_amdgcn_mfma_f32_16x16x32_f16(qa[mt], kb[nt], fz, 0, 0, 0);
            #pragma unroll
            for (int nt = 0; nt < 4; ++nt)
                sr[nt] += *reinterpret_cast<const f32x4*>(
                    biasfrag + ((((h * 4 + mt) * 4 + nt) * 64 + lane) << 2));
            if (boundary) {
                #pragma unroll
                for (int r = 0; r < 4; ++r) {
                    int q = mt * 16 + (g << 2) + r;
                    int lq = seg2((wh << 3) + (q >> 3)) * 3 + seg2((ww << 3) + (q & 7));
                    #pragma unroll
                    for (int nt = 0; nt < 4; ++nt) {
                        int k = nt * 16 + l15;
                        int lk = seg2((wh << 3) + (k >> 3)) * 3 + seg2((ww << 3) + (k & 7));
                        if (lq != lk) sr[nt][r] -= 100.0f;
                    }
                }
            }
            #pragma unroll
            for (int r = 0; r < 4; ++r) {
                float mx = fmaxf(fmaxf(sr[0][r], sr[1][r]), fmaxf(sr[2][r], sr[3][r]));
                mx = fmaxf(mx, __shfl_xor(mx, 1));
                mx = fmaxf(mx, __shfl_xor(mx, 2));
                mx = fmaxf(mx, __shfl_xor(mx, 4));
                mx = fmaxf(mx, __shfl_xor(mx, 8));
                float sm = 0.f;
                #pragma unroll
                for (int nt = 0; nt < 4; ++nt) {
                    float e = __expf(sr[nt][r] - mx);
                    sr[nt][r] = e;
                    sm += e;
                }
                sm += __shfl_xor(sm, 1); sm += __shfl_xor(sm, 2);
                sm += __shfl_xor(sm, 4); sm += __shfl_xor(sm, 8);
                inv_[mt][r] = 1.0f / sm;
            }
            #pragma unroll
            for (int nt = 0; nt < 4; ++nt)
                ph[mt][nt] = f16x4{ (f16)sr[nt][0], (f16)sr[nt][1], (f16)sr[nt][2], (f16)sr[nt][3] };
        }

        f16x8 vf[2][2];
        #pragma unroll
        for (int nt = 0; nt < 2; ++nt)
            #pragma unroll
            for (int ks = 0; ks < 2; ++ks)
                vf[nt][ks] = *reinterpret_cast<const f16x8*>(
                    vp + (ks * 4 + g) * 256 + (nt * 16 + l15) * 8);

        // PV in two 32-key halves via the wave-private 4 KiB bounce
        f32x4 o[4][2];
        #pragma unroll
        for (int mt = 0; mt < 4; ++mt) { o[mt][0] = fz; o[mt][1] = fz; }
        #pragma unroll
        for (int half = 0; half < 2; ++half) {
            #pragma unroll
            for (int mt = 0; mt < 4; ++mt)
                #pragma unroll
                for (int nt2 = 0; nt2 < 2; ++nt2)
                    #pragma unroll
                    for (int r = 0; r < 4; ++r) {
                        int q = mt * 16 + (g << 2) + r;
                        int key = nt2 * 16 + l15;
                        *reinterpret_cast<f16*>(wb + ((q * 64 + key * 2) ^ ((q & 3) << 4))) =
                            ph[mt][half * 2 + nt2][r];
                    }
            #pragma unroll
            for (int mt = 0; mt < 4; ++mt) {
                int q = mt * 16 + l15;
                f16x8 pa = *reinterpret_cast<const f16x8*>(
                    wb + ((q * 64 + g * 16) ^ ((q & 3) << 4)));
                #pragma unroll
                for (int nt = 0; nt < 2; ++nt)
                    o[mt][nt] = __builtin_amdgcn_mfma_f32_16x16x32_f16(pa, vf[nt][half], o[mt][nt], 0, 0, 0);
            }
        }

        // normalized O -> ot strip [64 rows][ch 32h..]
        #pragma unroll
        for (int mt = 0; mt < 4; ++mt)
            #pragma unroll
            for (int r = 0; r < 4; ++r) {
                int q = mt * 16 + (g << 2) + r;
                float iv = inv_[mt][r];
                #pragma unroll
                for (int nt = 0; nt < 2; ++nt) {
                    int ch = (h << 5) + nt * 16 + l15;
                    *reinterpret_cast<f16*>(L + ((q * 512 + ch * 2) ^ ((q & 7) << 4))) =
                        (f16)(o[mt][nt][r] * iv);
                }
            }
    }
    __syncthreads();   // the ONLY block barrier

    // ---- fused proj: wave does ch strips {wv*32, (wv+4)*32}
    #pragma unroll 1
    for (int sp = 0; sp < 2; ++sp) {
        const int c0 = ((wv + sp * 4) << 5);
        f32x4 pc[4][2];
        #pragma unroll
        for (int mt = 0; mt < 4; ++mt) { pc[mt][0] = fz; pc[mt][1] = fz; }
        #pragma unroll
        for (int ks = 0; ks < 8; ++ks) {
            f16x8 a[4], bfr[2];
            #pragma unroll
            for (int mt = 0; mt < 4; ++mt) {
                int q = mt * 16 + l15;
                a[mt] = *reinterpret_cast<const f16x8*>(
                    L + ((q * 512 + ks * 64 + g * 16) ^ ((q & 7) << 4)));
            }
            #pragma unroll
            for (int nt = 0; nt < 2; ++nt)
                bfr[nt] = *reinterpret_cast<const f16x8*>(
                    p_t + (c0 + nt * 16 + l15) * 256 + ks * 32 + g * 8);
            #pragma unroll
            for (int mt = 0; mt < 4; ++mt)
                #pragma unroll
                for (int nt = 0; nt < 2; ++nt)
                    pc[mt][nt] = __builtin_amdgcn_mfma_f32_16x16x32_f16(a[mt], bfr[nt], pc[mt][nt], 0, 0, 0);
        }
        float pb0 = proj_b[c0 + l15], pb1 = proj_b[c0 + 16 + l15];
        #pragma unroll
        for (int mt = 0; mt < 4; ++mt)
            #pragma unroll
            for (int r = 0; r < 4; ++r) {
                int q = mt * 16 + (g << 2) + r;
                int i = ((wh << 3) + (q >> 3) + 4) & 255;   // roll(+4) un-partition
                int j = ((ww << 3) + (q & 7) + 4) & 255;
                long addr = (((long)bb * 256 + i) * 256 + j) * 256;
                out[addr + c0 + l15]      = pc[mt][0][r] + pb0;
                out[addr + c0 + 16 + l15] = pc[mt][1][r] + pb1;
            }
    }
}

extern "C" void kernel_launch(void* const* d_in, const int* in_sizes, int n_in,
                              void* d_out, int out_size, void* d_ws, size_t ws_size,
                              hipStream_t stream) {
    const float* x      = (const float*)d_in[0];
    const float* qkv_w  = (const float*)d_in[1];
    const float* q_bias = (const float*)d_in[2];
    const float* v_bias = (const float*)d_in[3];
    const float* scale  = (const float*)d_in[4];
    const float* cpb_w1 = (const float*)d_in[5];
    const float* cpb_b1 = (const float*)d_in[6];
    const float* cpb_w2 = (const float*)d_in[7];
    const float* proj_w = (const float*)d_in[8];
    const float* proj_b = (const float*)d_in[9];
    float* out = (float*)d_out;

    char* ws = (char*)d_ws;
    float* biasfrag = (float*)(ws);                         // 128 KiB
    f16* w_t  = (f16*)(ws + 131072);                        // 384 KiB
    f16* p_t  = (f16*)(ws + 524288);                        // 128 KiB
    f16* qbuf = (f16*)(ws + (1u << 20));                    // 64 MiB
    f16* kbuf = (f16*)(ws + (1u << 20) + (1u << 26));       // 64 MiB
    f16* vtbuf = (f16*)(ws + (1u << 20) + 2u * (1u << 26)); // 64 MiB

    hipLaunchKernelGGL(k_prep, dim3(129), dim3(512), 0, stream,
                       cpb_w1, cpb_b1, cpb_w2, qkv_w, proj_w, biasfrag, w_t, p_t);
    hipLaunchKernelGGL(k_qkv, dim3(2048), dim3(256), 0, stream,
                       x, w_t, q_bias, v_bias, scale, qbuf, kbuf, vtbuf);
    hipLaunchKernelGGL(k_attn_proj, dim3(2048), dim3(256), 0, stream,
                       qbuf, kbuf, vtbuf, biasfrag, p_t, proj_b, out);
}